// Round 5
// baseline (95.227 us; speedup 1.0000x reference)
//
#include <hip/hip_runtime.h>
#include <stdint.h>

#define O_DIM 512
#define D_DIM 128
#define LR 0.01f
// 1 / (2 * sigma^2), sigma = 256 -> 1/131072
#define INV2SIG2 7.62939453125e-6f

typedef float f32x4 __attribute__((ext_vector_type(4)));

// ---------------- fast path ----------------
// ws layout: [0, 1 MiB) : dist[512][512] float
//
// Fused column-owner kernel: block j owns W[:, j, :] (256 KB).
//   Phase A: read column, compute dist[:, j] and the COMPLETE S[j].
//   Phase B: re-read the column (cache-hot) and stream
//            out[:, j, :] = W[:, j, :] + S[j], nontemporal store.
// 512 threads/block (8 waves) -> 2 blocks/CU -> 16 waves/CU (grid was the
// occupancy limiter at 256 threads: 2048 waves = 8 waves/CU, 19% occ).
__global__ __launch_bounds__(512, 4) void som_fused(
    const float* __restrict__ X,
    const float* __restrict__ W,
    float* __restrict__ dist,
    float* __restrict__ outW)
{
    const int j    = blockIdx.x;         // 0..511
    const int wave = threadIdx.x >> 6;   // 0..7
    const int lane = threadIdx.x & 63;
    const int g    = lane >> 4;          // b-subgroup 0..3
    const int i16  = lane & 15;          // d-slice within row
    const int dA   = i16 * 4;            // floats [dA, dA+4)
    const int dB   = 64 + dA;            // floats [dB, dB+4)

    float acc[8];
    #pragma unroll
    for (int u = 0; u < 8; ++u) acc[u] = 0.f;

    const int bbase = wave * 4 + g;      // 0..31; b = bbase + k*32, k=0..15

    // ---------------- phase A ----------------
    #pragma unroll
    for (int kb = 0; kb < 4; ++kb) {
        float4 wa[4], wb[4], xa[4], xb[4];
        int bb[4];
        #pragma unroll
        for (int u = 0; u < 4; ++u) {
            bb[u] = bbase + (kb * 4 + u) * 32;
            const float* wrow = W + ((size_t)bb[u] * O_DIM + j) * D_DIM;
            const float* xrow = X + (size_t)bb[u] * D_DIM;
            wa[u] = *(const float4*)(wrow + dA);
            wb[u] = *(const float4*)(wrow + dB);
            xa[u] = *(const float4*)(xrow + dA);
            xb[u] = *(const float4*)(xrow + dB);
        }
        #pragma unroll
        for (int u = 0; u < 4; ++u) {
            float dx[8];
            dx[0] = wa[u].x - xa[u].x; dx[1] = wa[u].y - xa[u].y;
            dx[2] = wa[u].z - xa[u].z; dx[3] = wa[u].w - xa[u].w;
            dx[4] = wb[u].x - xb[u].x; dx[5] = wb[u].y - xb[u].y;
            dx[6] = wb[u].z - xb[u].z; dx[7] = wb[u].w - xb[u].w;

            float s = 0.f;
            #pragma unroll
            for (int v = 0; v < 8; ++v) s = fmaf(dx[v], dx[v], s);
            // reduce across the 16 lanes of this b
            s += __shfl_xor(s, 1, 64);
            s += __shfl_xor(s, 2, 64);
            s += __shfl_xor(s, 4, 64);
            s += __shfl_xor(s, 8, 64);

            if (i16 == 0) dist[(size_t)bb[u] * O_DIM + j] = s;

            const float c = LR * __expf(-s * INV2SIG2);
            #pragma unroll
            for (int v = 0; v < 8; ++v) acc[v] = fmaf(-c, dx[v], acc[v]); // c*(x-w)
        }
    }

    // ---- reduce acc across b-subgroups (lanes i16, +16, +32, +48) ----
    #pragma unroll
    for (int u = 0; u < 8; ++u) {
        acc[u] += __shfl_xor(acc[u], 16, 64);
        acc[u] += __shfl_xor(acc[u], 32, 64);
    }

    __shared__ float sacc[8][D_DIM];
    __shared__ float sS[D_DIM];
    if (g == 0) {
        #pragma unroll
        for (int u = 0; u < 4; ++u) {
            sacc[wave][dA + u] = acc[u];
            sacc[wave][dB + u] = acc[4 + u];
        }
    }
    __syncthreads();
    if (threadIdx.x < D_DIM) {
        const int d = threadIdx.x;
        float t = sacc[0][d];
        #pragma unroll
        for (int w = 1; w < 8; ++w) t += sacc[w][d];
        sS[d] = t;
    }
    __syncthreads();

    const f32x4 sA = *(const f32x4*)(sS + dA);
    const f32x4 sB = *(const f32x4*)(sS + dB);

    // ---------------- phase B: out[:, j, :] = W[:, j, :] + S[j] ----------------
    #pragma unroll 4
    for (int k = 0; k < 16; ++k) {
        const int b = bbase + k * 32;
        const size_t e = ((size_t)b * O_DIM + j) * D_DIM;
        const f32x4 w4a = *(const f32x4*)(W + e + dA);
        const f32x4 w4b = *(const f32x4*)(W + e + dB);
        __builtin_nontemporal_store(w4a + sA, (f32x4*)(outW + e + dA));
        __builtin_nontemporal_store(w4b + sB, (f32x4*)(outW + e + dB));
    }
}

// row-wise argmin over j for each b
__global__ __launch_bounds__(64) void som_argmin(
    const float* __restrict__ dist,
    float* __restrict__ out)
{
    const int b = blockIdx.x;
    const int lane = threadIdx.x;
    unsigned long long best = ~0ull;
    #pragma unroll
    for (int k = 0; k < 8; ++k) {
        const int jj = k * 64 + lane;
        const float s = dist[(size_t)b * O_DIM + jj];
        const unsigned long long key =
            ((unsigned long long)__float_as_uint(s) << 32) | (unsigned int)jj;
        best = key < best ? key : best;
    }
    #pragma unroll
    for (int m = 32; m >= 1; m >>= 1) {
        const unsigned long long o = __shfl_xor(best, m, 64);
        best = o < best ? o : best;
    }
    if (lane == 0) out[b] = (float)(unsigned int)(best & 0xFFFFFFFFull);
}

// ---------------- fallback path (atomics, small ws) ----------------

__global__ __launch_bounds__(256) void som_pass1_atomic(
    const float* __restrict__ X, const float* __restrict__ W,
    float* __restrict__ S, unsigned long long* __restrict__ wkey)
{
    const int j = blockIdx.x >> 2, chunk = blockIdx.x & 3;
    const int wave = threadIdx.x >> 6, lane = threadIdx.x & 63;
    const int d0 = lane * 2;
    float accx = 0.f, accy = 0.f;
    const int b_end = chunk * 128 + 128;
    for (int b = chunk * 128 + wave; b < b_end; b += 4) {
        const float2 w2 = *(const float2*)(W + ((size_t)b * O_DIM + j) * D_DIM + d0);
        const float2 x2 = *(const float2*)(X + (size_t)b * D_DIM + d0);
        const float dx = w2.x - x2.x, dy = w2.y - x2.y;
        float s = dx * dx + dy * dy;
        #pragma unroll
        for (int m = 32; m >= 1; m >>= 1) s += __shfl_xor(s, m, 64);
        if (lane == 0)
            atomicMin(&wkey[b], ((unsigned long long)__float_as_uint(s) << 32) | (unsigned)j);
        const float c = LR * __expf(-s * INV2SIG2);
        accx -= c * dx; accy -= c * dy;
    }
    __shared__ float sacc[D_DIM];
    if (threadIdx.x < D_DIM) sacc[threadIdx.x] = 0.f;
    __syncthreads();
    atomicAdd(&sacc[d0], accx); atomicAdd(&sacc[d0 + 1], accy);
    __syncthreads();
    if (threadIdx.x < D_DIM) atomicAdd(&S[(size_t)j * D_DIM + threadIdx.x], sacc[threadIdx.x]);
}

__global__ __launch_bounds__(256) void som_pass2_atomic(
    const float* __restrict__ W, const float* __restrict__ S,
    const unsigned long long* __restrict__ wkey, float* __restrict__ out)
{
    const size_t tid = (size_t)blockIdx.x * blockDim.x + threadIdx.x;
    if (tid < O_DIM) out[tid] = (float)(unsigned int)(wkey[tid] & 0xFFFFFFFFull);
    float* __restrict__ outW = out + O_DIM;
    const size_t total4 = (size_t)O_DIM * O_DIM * D_DIM / 4;
    const size_t stride = (size_t)gridDim.x * blockDim.x;
    for (size_t i = tid; i < total4; i += stride) {
        const size_t e = i * 4;
        const float4 w4 = *(const float4*)(W + e);
        const float4 s4 = *(const float4*)(S + (e & (size_t)(O_DIM * D_DIM - 1)));
        float4 o4 = {w4.x + s4.x, w4.y + s4.y, w4.z + s4.z, w4.w + s4.w};
        *(float4*)(outW + e) = o4;
    }
}

extern "C" void kernel_launch(void* const* d_in, const int* in_sizes, int n_in,
                              void* d_out, int out_size, void* d_ws, size_t ws_size,
                              hipStream_t stream)
{
    const float* X = (const float*)d_in[0];   // (512, 128)
    const float* W = (const float*)d_in[1];   // (512, 512, 128)
    float* out = (float*)d_out;               // 512 winners + 512*512*128 weights

    const size_t DIST_BYTES = (size_t)O_DIM * O_DIM * sizeof(float);   // 1 MiB

    if (ws_size >= DIST_BYTES) {
        float* dist = (float*)d_ws;
        som_fused <<<dim3(512), dim3(512), 0, stream>>>(X, W, dist, out + O_DIM);
        som_argmin<<<dim3(512), dim3(64),  0, stream>>>(dist, out);
    } else {
        float* S = (float*)d_ws;
        unsigned long long* wkey =
            (unsigned long long*)((char*)d_ws + (size_t)O_DIM * D_DIM * sizeof(float));
        hipMemsetAsync(S, 0, (size_t)O_DIM * D_DIM * sizeof(float), stream);
        hipMemsetAsync(wkey, 0xFF, (size_t)O_DIM * sizeof(unsigned long long), stream);
        som_pass1_atomic<<<dim3(2048), dim3(256), 0, stream>>>(X, W, S, wkey);
        som_pass2_atomic<<<dim3(2048), dim3(256), 0, stream>>>(W, S, wkey, out);
    }
}

// Round 6
// 67.643 us; speedup vs baseline: 1.4078x; 1.4078x over previous
//
#include <hip/hip_runtime.h>
#include <stdint.h>

#define O_DIM 512
#define D_DIM 128
#define LR 0.01f
// 1 / (2 * sigma^2), sigma = 256 -> 1/131072
#define INV2SIG2 7.62939453125e-6f

typedef float f32x4 __attribute__((ext_vector_type(4)));

// ---------------- fast path ----------------
// ws layout:
//   [0, 1 MiB)        : dist[512][512]     float
//   [1 MiB, 1.5 MiB)  : Spart[512][2][128] float  (indexed (j*2+h)*128+d)
//
// Kernel A: block (j, h) owns half-column W[h*256 .. h*256+255, j, :] (128 KB).
//   Computes dist rows for its half and the half's partial S -> Spart.
//   grid 1024 x 256thr -> 4 blocks/CU -> 16 waves/CU (Round-4's 512-block
//   grid capped occupancy at 8 waves/CU; Round-5's 512-thr blocks spilled).
// Kernel B: folds Spart halves into registers, fused row-argmin (blocks
//   0..511), streams out[:,j,:] = W + S[j] over the half-column (W L3-hot,
//   nontemporal store).
__global__ __launch_bounds__(256) void som_passA(
    const float* __restrict__ X,
    const float* __restrict__ W,
    float* __restrict__ dist,
    float* __restrict__ Spart)
{
    const int j    = blockIdx.x >> 1;    // 0..511
    const int h    = blockIdx.x & 1;     // half
    const int wave = threadIdx.x >> 6;   // 0..3
    const int lane = threadIdx.x & 63;
    const int g    = lane >> 4;          // b-subgroup 0..3
    const int i16  = lane & 15;          // d-slice within row
    const int dA   = i16 * 4;            // floats [dA, dA+4)
    const int dB   = 64 + dA;            // floats [dB, dB+4)

    float acc[8];
    #pragma unroll
    for (int u = 0; u < 8; ++u) acc[u] = 0.f;

    const int bbase = h * 256 + wave * 4 + g;   // + k*16, k = 0..15

    #pragma unroll
    for (int kb = 0; kb < 4; ++kb) {
        float4 wa[4], wb[4], xa[4], xb[4];
        int bb[4];
        #pragma unroll
        for (int u = 0; u < 4; ++u) {
            bb[u] = bbase + (kb * 4 + u) * 16;
            const float* wrow = W + ((size_t)bb[u] * O_DIM + j) * D_DIM;
            const float* xrow = X + (size_t)bb[u] * D_DIM;
            wa[u] = *(const float4*)(wrow + dA);
            wb[u] = *(const float4*)(wrow + dB);
            xa[u] = *(const float4*)(xrow + dA);
            xb[u] = *(const float4*)(xrow + dB);
        }
        #pragma unroll
        for (int u = 0; u < 4; ++u) {
            float dx[8];
            dx[0] = wa[u].x - xa[u].x; dx[1] = wa[u].y - xa[u].y;
            dx[2] = wa[u].z - xa[u].z; dx[3] = wa[u].w - xa[u].w;
            dx[4] = wb[u].x - xb[u].x; dx[5] = wb[u].y - xb[u].y;
            dx[6] = wb[u].z - xb[u].z; dx[7] = wb[u].w - xb[u].w;

            float s = 0.f;
            #pragma unroll
            for (int v = 0; v < 8; ++v) s = fmaf(dx[v], dx[v], s);
            // reduce across the 16 lanes of this b
            s += __shfl_xor(s, 1, 64);
            s += __shfl_xor(s, 2, 64);
            s += __shfl_xor(s, 4, 64);
            s += __shfl_xor(s, 8, 64);

            if (i16 == 0) dist[(size_t)bb[u] * O_DIM + j] = s;

            const float c = LR * __expf(-s * INV2SIG2);
            #pragma unroll
            for (int v = 0; v < 8; ++v) acc[v] = fmaf(-c, dx[v], acc[v]); // c*(x-w)
        }
    }

    // ---- reduce acc across b-subgroups (lanes i16, +16, +32, +48) ----
    #pragma unroll
    for (int u = 0; u < 8; ++u) {
        acc[u] += __shfl_xor(acc[u], 16, 64);
        acc[u] += __shfl_xor(acc[u], 32, 64);
    }

    __shared__ float sacc[4][D_DIM];
    if (g == 0) {
        #pragma unroll
        for (int u = 0; u < 4; ++u) {
            sacc[wave][dA + u] = acc[u];
            sacc[wave][dB + u] = acc[4 + u];
        }
    }
    __syncthreads();
    if (threadIdx.x < D_DIM) {
        const int d = threadIdx.x;
        Spart[((size_t)j * 2 + h) * D_DIM + d] =
            sacc[0][d] + sacc[1][d] + sacc[2][d] + sacc[3][d];
    }
}

__global__ __launch_bounds__(256) void som_passB(
    const float* __restrict__ W,
    const float* __restrict__ dist,
    const float* __restrict__ Spart,
    float* __restrict__ out)
{
    const int j = blockIdx.x >> 1;    // 0..511
    const int h = blockIdx.x & 1;     // half
    const int t = threadIdx.x;
    float* __restrict__ outW = out + O_DIM;

    // ---- fused argmin for row b = blockIdx.x (first wave of blocks 0..511) ----
    if (blockIdx.x < O_DIM && t < 64) {
        const int b = blockIdx.x;
        unsigned long long best = ~0ull;
        #pragma unroll
        for (int k = 0; k < 8; ++k) {
            const int jj = k * 64 + t;
            const float s = dist[(size_t)b * O_DIM + jj];
            const unsigned long long key =
                ((unsigned long long)__float_as_uint(s) << 32) | (unsigned int)jj;
            best = key < best ? key : best;
        }
        #pragma unroll
        for (int m = 32; m >= 1; m >>= 1) {
            const unsigned long long o = __shfl_xor(best, m, 64);
            best = o < best ? o : best;
        }
        if (t == 0) out[b] = (float)(unsigned int)(best & 0xFFFFFFFFull);
    }

    const int wave = t >> 6;
    const int lane = t & 63;
    const int g    = lane >> 4;
    const int i16  = lane & 15;
    const int dA   = i16 * 4;
    const int dB   = 64 + dA;

    // ---- fold Spart's two halves straight into registers (L2-hot) ----
    const float* sp0 = Spart + ((size_t)j * 2) * D_DIM;
    const float* sp1 = sp0 + D_DIM;
    const f32x4 sA = *(const f32x4*)(sp0 + dA) + *(const f32x4*)(sp1 + dA);
    const f32x4 sB = *(const f32x4*)(sp0 + dB) + *(const f32x4*)(sp1 + dB);

    // ---- stream: out[b, j, :] = W[b, j, :] + S[j] over this half-column ----
    const int bbase = h * 256 + wave * 4 + g;   // + k*16, k = 0..15
    #pragma unroll 4
    for (int k = 0; k < 16; ++k) {
        const int b = bbase + k * 16;
        const size_t e = ((size_t)b * O_DIM + j) * D_DIM;
        const f32x4 w4a = *(const f32x4*)(W + e + dA);
        const f32x4 w4b = *(const f32x4*)(W + e + dB);
        __builtin_nontemporal_store(w4a + sA, (f32x4*)(outW + e + dA));
        __builtin_nontemporal_store(w4b + sB, (f32x4*)(outW + e + dB));
    }
}

// ---------------- fallback path (atomics, small ws) ----------------

__global__ __launch_bounds__(256) void som_pass1_atomic(
    const float* __restrict__ X, const float* __restrict__ W,
    float* __restrict__ S, unsigned long long* __restrict__ wkey)
{
    const int j = blockIdx.x >> 2, chunk = blockIdx.x & 3;
    const int wave = threadIdx.x >> 6, lane = threadIdx.x & 63;
    const int d0 = lane * 2;
    float accx = 0.f, accy = 0.f;
    const int b_end = chunk * 128 + 128;
    for (int b = chunk * 128 + wave; b < b_end; b += 4) {
        const float2 w2 = *(const float2*)(W + ((size_t)b * O_DIM + j) * D_DIM + d0);
        const float2 x2 = *(const float2*)(X + (size_t)b * D_DIM + d0);
        const float dx = w2.x - x2.x, dy = w2.y - x2.y;
        float s = dx * dx + dy * dy;
        #pragma unroll
        for (int m = 32; m >= 1; m >>= 1) s += __shfl_xor(s, m, 64);
        if (lane == 0)
            atomicMin(&wkey[b], ((unsigned long long)__float_as_uint(s) << 32) | (unsigned)j);
        const float c = LR * __expf(-s * INV2SIG2);
        accx -= c * dx; accy -= c * dy;
    }
    __shared__ float sacc[D_DIM];
    if (threadIdx.x < D_DIM) sacc[threadIdx.x] = 0.f;
    __syncthreads();
    atomicAdd(&sacc[d0], accx); atomicAdd(&sacc[d0 + 1], accy);
    __syncthreads();
    if (threadIdx.x < D_DIM) atomicAdd(&S[(size_t)j * D_DIM + threadIdx.x], sacc[threadIdx.x]);
}

__global__ __launch_bounds__(256) void som_pass2_atomic(
    const float* __restrict__ W, const float* __restrict__ S,
    const unsigned long long* __restrict__ wkey, float* __restrict__ out)
{
    const size_t tid = (size_t)blockIdx.x * blockDim.x + threadIdx.x;
    if (tid < O_DIM) out[tid] = (float)(unsigned int)(wkey[tid] & 0xFFFFFFFFull);
    float* __restrict__ outW = out + O_DIM;
    const size_t total4 = (size_t)O_DIM * O_DIM * D_DIM / 4;
    const size_t stride = (size_t)gridDim.x * blockDim.x;
    for (size_t i = tid; i < total4; i += stride) {
        const size_t e = i * 4;
        const float4 w4 = *(const float4*)(W + e);
        const float4 s4 = *(const float4*)(S + (e & (size_t)(O_DIM * D_DIM - 1)));
        float4 o4 = {w4.x + s4.x, w4.y + s4.y, w4.z + s4.z, w4.w + s4.w};
        *(float4*)(outW + e) = o4;
    }
}

extern "C" void kernel_launch(void* const* d_in, const int* in_sizes, int n_in,
                              void* d_out, int out_size, void* d_ws, size_t ws_size,
                              hipStream_t stream)
{
    const float* X = (const float*)d_in[0];   // (512, 128)
    const float* W = (const float*)d_in[1];   // (512, 512, 128)
    float* out = (float*)d_out;               // 512 winners + 512*512*128 weights

    const size_t DIST_BYTES  = (size_t)O_DIM * O_DIM * sizeof(float);       // 1 MiB
    const size_t SPART_BYTES = 2ull * O_DIM * D_DIM * sizeof(float);        // 512 KiB

    if (ws_size >= DIST_BYTES + SPART_BYTES) {
        float* dist  = (float*)d_ws;
        float* Spart = (float*)((char*)d_ws + DIST_BYTES);
        som_passA<<<dim3(1024), dim3(256), 0, stream>>>(X, W, dist, Spart);
        som_passB<<<dim3(1024), dim3(256), 0, stream>>>(W, dist, Spart, out);
    } else {
        float* S = (float*)d_ws;
        unsigned long long* wkey =
            (unsigned long long*)((char*)d_ws + (size_t)O_DIM * D_DIM * sizeof(float));
        hipMemsetAsync(S, 0, (size_t)O_DIM * D_DIM * sizeof(float), stream);
        hipMemsetAsync(wkey, 0xFF, (size_t)O_DIM * sizeof(unsigned long long), stream);
        som_pass1_atomic<<<dim3(2048), dim3(256), 0, stream>>>(X, W, S, wkey);
        som_pass2_atomic<<<dim3(2048), dim3(256), 0, stream>>>(W, S, wkey, out);
    }
}